// Round 5
// baseline (48.900 us; speedup 1.0000x reference)
//
#include <hip/hip_runtime.h>
#include <stdint.h>

#define KSEL 10
#define NTHREADS 512
#define CAP 2560            // candidate slots; fallback uses two-stage merge to fit
#define BUFSZ (CAP + 16)
#define NWAVES (NTHREADS / 64)

__device__ __forceinline__ unsigned long long ullmin(unsigned long long a, unsigned long long b) {
    return a < b ? a : b;
}

__global__ void __launch_bounds__(NTHREADS)
knn_topk_kernel(const float* __restrict__ ged, const float* __restrict__ y,
                const float* __restrict__ coef, float* __restrict__ out, int n_train)
{
    __shared__ unsigned long long sbuf[BUFSZ];
    __shared__ unsigned long long wmin[NWAVES];
    __shared__ unsigned long long winner;
    __shared__ unsigned long long topk[KSEL];
    __shared__ int cnt;

    const int tid = threadIdx.x;
    const int row = blockIdx.x;
    const float* __restrict__ x = ged + (size_t)row * (size_t)n_train;

    // vector path only if aligned/divisible (true here: 50000 % 4 == 0)
    const int n4 = ((n_train & 3) == 0) ? (n_train >> 2) : 0;
    const float4* __restrict__ x4 = (const float4*)x;

    int len = -1;
    float T = 2.0e-3f;

#define PROC(v, base)                                                                                            \
    do {                                                                                                         \
        if ((v).x < T) { int p = atomicAdd(&cnt, 1); if (p < CAP) sbuf[p] = ((unsigned long long)__float_as_uint((v).x) << 32) | (unsigned)((base)    ); } \
        if ((v).y < T) { int p = atomicAdd(&cnt, 1); if (p < CAP) sbuf[p] = ((unsigned long long)__float_as_uint((v).y) << 32) | (unsigned)((base) + 1); } \
        if ((v).z < T) { int p = atomicAdd(&cnt, 1); if (p < CAP) sbuf[p] = ((unsigned long long)__float_as_uint((v).z) << 32) | (unsigned)((base) + 2); } \
        if ((v).w < T) { int p = atomicAdd(&cnt, 1); if (p < CAP) sbuf[p] = ((unsigned long long)__float_as_uint((v).w) << 32) | (unsigned)((base) + 3); } \
    } while (0)

    for (int attempt = 0; attempt < 24; ++attempt) {
        if (tid == 0) cnt = 0;
        __syncthreads();

        // paired independent loads: 2 float4s in flight per thread
        for (int i = tid; i < n4; i += 2 * NTHREADS) {
            int i2 = i + NTHREADS;
            float4 a = x4[i];
            float4 b;
            bool h2 = (i2 < n4);
            if (h2) b = x4[i2];
            PROC(a, i << 2);
            if (h2) PROC(b, i2 << 2);
        }
        for (int i = (n4 << 2) + tid; i < n_train; i += NTHREADS) {
            float v = x[i];
            if (v < T) { int p = atomicAdd(&cnt, 1); if (p < CAP) sbuf[p] = ((unsigned long long)__float_as_uint(v) << 32) | (unsigned)i; }
        }
        __syncthreads();

        int c = cnt;                         // uniform across block
        if (c >= KSEL && c <= CAP) { len = c; break; }
        T = (c < KSEL) ? T * 8.0f : T * 0.125f;
        __syncthreads();                     // protect cnt until everyone has read it
    }
#undef PROC

    if (len < 0) {
        // Exact fallback (any data distribution): per-thread sorted top-K,
        // two-stage merge so the dump fits in CAP slots.
        unsigned long long loc[KSEL];
        #pragma unroll
        for (int j = 0; j < KSEL; ++j) loc[j] = ~0ull;
        for (int i = tid; i < n_train; i += NTHREADS) {
            unsigned long long key = ((unsigned long long)__float_as_uint(x[i]) << 32) | (unsigned)i;
            if (key < loc[KSEL - 1]) {
                loc[KSEL - 1] = key;
                #pragma unroll
                for (int j = KSEL - 1; j > 0; --j) {
                    if (loc[j] < loc[j - 1]) {
                        unsigned long long t = loc[j]; loc[j] = loc[j - 1]; loc[j - 1] = t;
                    }
                }
            }
        }
        __syncthreads();
        // stage 1: upper half dumps its lists
        if (tid >= NTHREADS / 2) {
            #pragma unroll
            for (int j = 0; j < KSEL; ++j) sbuf[(tid - NTHREADS / 2) * KSEL + j] = loc[j];
        }
        __syncthreads();
        // stage 2: lower half merges partner's sorted list into its own top-K
        if (tid < NTHREADS / 2) {
            #pragma unroll
            for (int j = 0; j < KSEL; ++j) {
                unsigned long long key = sbuf[tid * KSEL + j];
                if (key < loc[KSEL - 1]) {
                    loc[KSEL - 1] = key;
                    #pragma unroll
                    for (int q = KSEL - 1; q > 0; --q) {
                        if (loc[q] < loc[q - 1]) {
                            unsigned long long t = loc[q]; loc[q] = loc[q - 1]; loc[q - 1] = t;
                        }
                    }
                }
            }
        }
        __syncthreads();
        if (tid < NTHREADS / 2) {
            #pragma unroll
            for (int j = 0; j < KSEL; ++j) sbuf[tid * KSEL + j] = loc[j];
        }
        __syncthreads();
        len = (NTHREADS / 2) * KSEL;
    }

    // Extract KSEL smallest keys from sbuf[0..len) — 10 rounds of min-with-removal.
    for (int r = 0; r < KSEL; ++r) {
        unsigned long long m = ~0ull;
        for (int j = tid; j < len; j += NTHREADS) m = ullmin(m, sbuf[j]);
        #pragma unroll
        for (int off = 32; off > 0; off >>= 1) m = ullmin(m, __shfl_down(m, off, 64));
        if ((tid & 63) == 0) wmin[tid >> 6] = m;
        __syncthreads();
        if (tid == 0) {
            unsigned long long w = wmin[0];
            #pragma unroll
            for (int q = 1; q < NWAVES; ++q) w = ullmin(w, wmin[q]);
            winner = w;
            topk[r] = w;
        }
        __syncthreads();
        unsigned long long w = winner;
        for (int j = tid; j < len; j += NTHREADS) if (sbuf[j] == w) sbuf[j] = ~0ull;
        __syncthreads();
    }

    if (tid == 0) {
        float cd = coef[0];
        float alpha = cd * cd;
        float ssum = 0.0f, swy = 0.0f;
        #pragma unroll
        for (int r = 0; r < KSEL; ++r) {
            unsigned long long key = topk[r];
            float v = __uint_as_float((unsigned)(key >> 32));
            int idx = (int)(unsigned)(key & 0xffffffffull);
            float s = expf(-alpha * v);
            ssum += s;
            swy  += s * y[idx];
        }
        out[row] = swy / ssum;
    }
}

extern "C" void kernel_launch(void* const* d_in, const int* in_sizes, int n_in,
                              void* d_out, int out_size, void* d_ws, size_t ws_size,
                              hipStream_t stream) {
    const float* ged  = (const float*)d_in[0];
    const float* y    = (const float*)d_in[1];
    const float* coef = (const float*)d_in[2];
    float* out = (float*)d_out;

    const int rows    = out_size;              // = NB_TEST = 1024
    const int n_train = in_sizes[0] / rows;    // = 50000

    knn_topk_kernel<<<rows, NTHREADS, 0, stream>>>(ged, y, coef, out, n_train);
}

// Round 6
// 44.205 us; speedup vs baseline: 1.1062x; 1.1062x over previous
//
#include <hip/hip_runtime.h>
#include <stdint.h>

#define KSEL 10
#define NTHREADS 256
#define CAP 2560            // candidate slots; also exactly fits fallback dump 256*10
#define BUFSZ (CAP + 16)
#define NWAVES (NTHREADS / 64)

__device__ __forceinline__ unsigned long long ullmin(unsigned long long a, unsigned long long b) {
    return a < b ? a : b;
}

__global__ void __launch_bounds__(NTHREADS)
knn_topk_kernel(const float* __restrict__ ged, const float* __restrict__ y,
                const float* __restrict__ coef, float* __restrict__ out, int n_train)
{
    __shared__ unsigned long long sbuf[BUFSZ];
    __shared__ unsigned long long wmin[NWAVES];
    __shared__ unsigned long long winner;
    __shared__ unsigned long long topk[KSEL];
    __shared__ int cnt;

    const int tid = threadIdx.x;
    const int row = blockIdx.x;
    const float* __restrict__ x = ged + (size_t)row * (size_t)n_train;

    // vector path only if divisible (true here: 50000 % 4 == 0)
    const int n4 = ((n_train & 3) == 0) ? (n_train >> 2) : 0;
    const float4* __restrict__ x4 = (const float4*)x;
    // main region: multiple of 4*NTHREADS float4s, processed with 4-deep ILP
    const int n4_main = n4 & ~(4 * NTHREADS - 1);

    int len = -1;
    float T = 2.0e-3f;

#define PROC(v, base)                                                                                            \
    do {                                                                                                         \
        if ((v).x < T) { int p = atomicAdd(&cnt, 1); if (p < CAP) sbuf[p] = ((unsigned long long)__float_as_uint((v).x) << 32) | (unsigned)((base)    ); } \
        if ((v).y < T) { int p = atomicAdd(&cnt, 1); if (p < CAP) sbuf[p] = ((unsigned long long)__float_as_uint((v).y) << 32) | (unsigned)((base) + 1); } \
        if ((v).z < T) { int p = atomicAdd(&cnt, 1); if (p < CAP) sbuf[p] = ((unsigned long long)__float_as_uint((v).z) << 32) | (unsigned)((base) + 2); } \
        if ((v).w < T) { int p = atomicAdd(&cnt, 1); if (p < CAP) sbuf[p] = ((unsigned long long)__float_as_uint((v).w) << 32) | (unsigned)((base) + 3); } \
    } while (0)

    for (int attempt = 0; attempt < 24; ++attempt) {
        if (tid == 0) cnt = 0;
        __syncthreads();

        // 4 independent float4 loads in flight per thread (64 B/lane ILP),
        // occupancy unchanged vs R1 (256 thr, 16 waves/CU, 4 blocks/CU).
        for (int i = tid; i < n4_main; i += 4 * NTHREADS) {
            float4 a = x4[i];
            float4 b = x4[i +     NTHREADS];
            float4 c = x4[i + 2 * NTHREADS];
            float4 d = x4[i + 3 * NTHREADS];
            PROC(a, (i               ) << 2);
            PROC(b, (i +     NTHREADS) << 2);
            PROC(c, (i + 2 * NTHREADS) << 2);
            PROC(d, (i + 3 * NTHREADS) << 2);
        }
        for (int i = n4_main + tid; i < n4; i += NTHREADS) {
            float4 v = x4[i];
            PROC(v, i << 2);
        }
        for (int i = (n4 << 2) + tid; i < n_train; i += NTHREADS) {
            float v = x[i];
            if (v < T) { int p = atomicAdd(&cnt, 1); if (p < CAP) sbuf[p] = ((unsigned long long)__float_as_uint(v) << 32) | (unsigned)i; }
        }
        __syncthreads();

        int c = cnt;                         // uniform across block
        if (c >= KSEL && c <= CAP) { len = c; break; }
        T = (c < KSEL) ? T * 8.0f : T * 0.125f;
        __syncthreads();                     // protect cnt until everyone has read it
    }
#undef PROC

    if (len < 0) {
        // Exact fallback (any data distribution): per-thread sorted top-K, then merge.
        unsigned long long loc[KSEL];
        #pragma unroll
        for (int j = 0; j < KSEL; ++j) loc[j] = ~0ull;
        for (int i = tid; i < n_train; i += NTHREADS) {
            unsigned long long key = ((unsigned long long)__float_as_uint(x[i]) << 32) | (unsigned)i;
            if (key < loc[KSEL - 1]) {
                loc[KSEL - 1] = key;
                #pragma unroll
                for (int j = KSEL - 1; j > 0; --j) {
                    if (loc[j] < loc[j - 1]) {
                        unsigned long long t = loc[j]; loc[j] = loc[j - 1]; loc[j - 1] = t;
                    }
                }
            }
        }
        __syncthreads();
        #pragma unroll
        for (int j = 0; j < KSEL; ++j) sbuf[tid * KSEL + j] = loc[j];
        __syncthreads();
        len = NTHREADS * KSEL;
    }

    // Extract KSEL smallest keys from sbuf[0..len) — 10 rounds of min-with-removal.
    for (int r = 0; r < KSEL; ++r) {
        unsigned long long m = ~0ull;
        for (int j = tid; j < len; j += NTHREADS) m = ullmin(m, sbuf[j]);
        #pragma unroll
        for (int off = 32; off > 0; off >>= 1) m = ullmin(m, __shfl_down(m, off, 64));
        if ((tid & 63) == 0) wmin[tid >> 6] = m;
        __syncthreads();
        if (tid == 0) {
            unsigned long long w = wmin[0];
            #pragma unroll
            for (int q = 1; q < NWAVES; ++q) w = ullmin(w, wmin[q]);
            winner = w;
            topk[r] = w;
        }
        __syncthreads();
        unsigned long long w = winner;
        for (int j = tid; j < len; j += NTHREADS) if (sbuf[j] == w) sbuf[j] = ~0ull;
        __syncthreads();
    }

    if (tid == 0) {
        float cd = coef[0];
        float alpha = cd * cd;
        float ssum = 0.0f, swy = 0.0f;
        #pragma unroll
        for (int r = 0; r < KSEL; ++r) {
            unsigned long long key = topk[r];
            float v = __uint_as_float((unsigned)(key >> 32));
            int idx = (int)(unsigned)(key & 0xffffffffull);
            float s = expf(-alpha * v);
            ssum += s;
            swy  += s * y[idx];
        }
        out[row] = swy / ssum;
    }
}

extern "C" void kernel_launch(void* const* d_in, const int* in_sizes, int n_in,
                              void* d_out, int out_size, void* d_ws, size_t ws_size,
                              hipStream_t stream) {
    const float* ged  = (const float*)d_in[0];
    const float* y    = (const float*)d_in[1];
    const float* coef = (const float*)d_in[2];
    float* out = (float*)d_out;

    const int rows    = out_size;              // = NB_TEST = 1024
    const int n_train = in_sizes[0] / rows;    // = 50000

    knn_topk_kernel<<<rows, NTHREADS, 0, stream>>>(ged, y, coef, out, n_train);
}

// Round 7
// 41.544 us; speedup vs baseline: 1.1771x; 1.0641x over previous
//
#include <hip/hip_runtime.h>
#include <stdint.h>

#define KSEL 10
#define NTHREADS 256
#define CAP 2560            // candidate slots; also exactly fits fallback dump 256*10
#define BUFSZ (CAP + 16)

__device__ __forceinline__ unsigned long long ullmin(unsigned long long a, unsigned long long b) {
    return a < b ? a : b;
}

__global__ void __launch_bounds__(NTHREADS)
knn_topk_kernel(const float* __restrict__ ged, const float* __restrict__ y,
                const float* __restrict__ coef, float* __restrict__ out, int n_train)
{
    __shared__ unsigned long long sbuf[BUFSZ];
    __shared__ int cnt;

    const int tid = threadIdx.x;
    const int row = blockIdx.x;
    const float* __restrict__ x = ged + (size_t)row * (size_t)n_train;

    // vector path only if divisible (true here: 50000 % 4 == 0)
    const int n4 = ((n_train & 3) == 0) ? (n_train >> 2) : 0;
    const float4* __restrict__ x4 = (const float4*)x;

    int len = -1;
    float T = 2.0e-3f;

#define PROC(v, base)                                                                                            \
    do {                                                                                                         \
        if ((v).x < T) { int p = atomicAdd(&cnt, 1); if (p < CAP) sbuf[p] = ((unsigned long long)__float_as_uint((v).x) << 32) | (unsigned)((base)    ); } \
        if ((v).y < T) { int p = atomicAdd(&cnt, 1); if (p < CAP) sbuf[p] = ((unsigned long long)__float_as_uint((v).y) << 32) | (unsigned)((base) + 1); } \
        if ((v).z < T) { int p = atomicAdd(&cnt, 1); if (p < CAP) sbuf[p] = ((unsigned long long)__float_as_uint((v).z) << 32) | (unsigned)((base) + 2); } \
        if ((v).w < T) { int p = atomicAdd(&cnt, 1); if (p < CAP) sbuf[p] = ((unsigned long long)__float_as_uint((v).w) << 32) | (unsigned)((base) + 3); } \
    } while (0)

    for (int attempt = 0; attempt < 24; ++attempt) {
        if (tid == 0) cnt = 0;
        __syncthreads();

        for (int i = tid; i < n4; i += NTHREADS) {
            float4 v = x4[i];
            PROC(v, i << 2);
        }
        for (int i = (n4 << 2) + tid; i < n_train; i += NTHREADS) {
            float v = x[i];
            if (v < T) { int p = atomicAdd(&cnt, 1); if (p < CAP) sbuf[p] = ((unsigned long long)__float_as_uint(v) << 32) | (unsigned)i; }
        }
        __syncthreads();

        int c = cnt;                         // uniform across block
        if (c >= KSEL && c <= CAP) { len = c; break; }
        T = (c < KSEL) ? T * 8.0f : T * 0.125f;
        __syncthreads();                     // protect cnt until everyone has read it
    }
#undef PROC

    if (len < 0) {
        // Exact fallback (any data distribution): per-thread sorted top-K, then merge.
        unsigned long long loc[KSEL];
        #pragma unroll
        for (int j = 0; j < KSEL; ++j) loc[j] = ~0ull;
        for (int i = tid; i < n_train; i += NTHREADS) {
            unsigned long long key = ((unsigned long long)__float_as_uint(x[i]) << 32) | (unsigned)i;
            if (key < loc[KSEL - 1]) {
                loc[KSEL - 1] = key;
                #pragma unroll
                for (int j = KSEL - 1; j > 0; --j) {
                    if (loc[j] < loc[j - 1]) {
                        unsigned long long t = loc[j]; loc[j] = loc[j - 1]; loc[j - 1] = t;
                    }
                }
            }
        }
        __syncthreads();
        #pragma unroll
        for (int j = 0; j < KSEL; ++j) sbuf[tid * KSEL + j] = loc[j];
        __syncthreads();
        len = NTHREADS * KSEL;
    }

    // ---- wave-0-only, barrier-free extraction ----
    // Each sbuf slot j is owned by lane (j & 63): removal writes and next-round
    // reads of a slot always happen in the same lane -> no cross-lane hazard.
    if (tid >= 64) return;

    unsigned long long mykey = ~0ull;   // lane r ends up holding winner r (r < KSEL)

    #pragma unroll
    for (int r = 0; r < KSEL; ++r) {
        unsigned long long m = ~0ull;
        for (int j = tid; j < len; j += 64) m = ullmin(m, sbuf[j]);
        #pragma unroll
        for (int off = 32; off > 0; off >>= 1)
            m = ullmin(m, __shfl_xor((long long)m, off, 64));
        // all lanes now hold the round-r winner
        if (tid == r) mykey = m;
        for (int j = tid; j < len; j += 64) if (sbuf[j] == m) sbuf[j] = ~0ull;
    }

    // lanes 0..KSEL-1 gather y and compute exp weights in parallel
    float s = 0.0f, wy = 0.0f;
    if (tid < KSEL) {
        float cd = coef[0];
        float alpha = cd * cd;
        float v = __uint_as_float((unsigned)(mykey >> 32));
        int idx = (int)(unsigned)(mykey & 0xffffffffull);
        s  = expf(-alpha * v);
        wy = s * y[idx];
    }
    #pragma unroll
    for (int off = 32; off > 0; off >>= 1) {
        s  += __shfl_xor(s,  off, 64);
        wy += __shfl_xor(wy, off, 64);
    }
    if (tid == 0) out[row] = wy / s;
}

extern "C" void kernel_launch(void* const* d_in, const int* in_sizes, int n_in,
                              void* d_out, int out_size, void* d_ws, size_t ws_size,
                              hipStream_t stream) {
    const float* ged  = (const float*)d_in[0];
    const float* y    = (const float*)d_in[1];
    const float* coef = (const float*)d_in[2];
    float* out = (float*)d_out;

    const int rows    = out_size;              // = NB_TEST = 1024
    const int n_train = in_sizes[0] / rows;    // = 50000

    knn_topk_kernel<<<rows, NTHREADS, 0, stream>>>(ged, y, coef, out, n_train);
}